// Round 1
// baseline (878.314 us; speedup 1.0000x reference)
//
#include <hip/hip_runtime.h>

typedef __attribute__((ext_vector_type(4))) float f32x4;
typedef __attribute__((ext_vector_type(8))) short short8;
typedef unsigned short u16;
typedef unsigned int u32;

__device__ __forceinline__ u16 f2bf(float f){
  u32 x = __float_as_uint(f);
  u32 r = x + 0x7fffu + ((x >> 16) & 1u);
  return (u16)(r >> 16);
}
__device__ __forceinline__ float bf2f(u16 u){ return __uint_as_float(((u32)u) << 16); }

__device__ __forceinline__ void gld_lds16(const u16* g, u16* l){
  __builtin_amdgcn_global_load_lds((const __attribute__((address_space(1))) void*)g,
                                   (__attribute__((address_space(3))) void*)l, 16, 0, 0);
}

__device__ __forceinline__ f32x4 mfma16(short8 a, short8 b, f32x4 c){
  return __builtin_amdgcn_mfma_f32_16x16x32_bf16(a, b, c, 0, 0, 0);
}

__device__ __forceinline__ float sigf(float x){
  return __builtin_amdgcn_rcpf(1.0f + __expf(-x));
}
__device__ __forceinline__ float tanhf_(float x){
  float e = __expf(2.0f * x);
  return 1.0f - 2.0f * __builtin_amdgcn_rcpf(e + 1.0f);
}

// ---------------- cast f32 -> bf16 ----------------
__global__ void k_cast(const float* __restrict__ in, u16* __restrict__ out, int n4){
  int i = blockIdx.x * 256 + threadIdx.x;
  if (i < n4){
    float4 v = ((const float4*)in)[i];
    ushort4 o; o.x=f2bf(v.x); o.y=f2bf(v.y); o.z=f2bf(v.z); o.w=f2bf(v.w);
    ((ushort4*)out)[i] = o;
  }
}

// ---------------- GEMM: A[M,K] row-major, B[N,K] row-major (B^T), bf16 in, f32 acc ----
// MODE 0: +bias1+bias2, store bf16 to xp[dir][s'][b][g] (time-reversed for dir>=6)
// MODE 1: +bias1, exact gelu, store bf16 row-major [M,N]
// MODE 2: +bias1, store f32 row-major [M,N]
template<int MODE>
__global__ __launch_bounds__(256) void k_gemm(const u16* __restrict__ A, const u16* __restrict__ B,
                       void* __restrict__ C, const float* __restrict__ bias1,
                       const float* __restrict__ bias2, int M, int N, int K)
{
  __shared__ __align__(16) u16 lA[128*64];
  __shared__ __align__(16) u16 lB[128*64];
  int nbm = M >> 7;
  int nwg = gridDim.x;
  int bid = blockIdx.x;
  int q = nwg >> 3;                        // nwg always divisible by 8 here
  int swz = (bid & 7) * q + (bid >> 3);    // XCD-aware swizzle (bijective)
  int bm = swz % nbm, bn = swz / nbm;
  int tid = threadIdx.x, lane = tid & 63;
  int wv = tid >> 6;
  int wrow = (wv & 1) << 6, wcol = (wv >> 1) << 6;
  int l15 = lane & 15, lhi = lane >> 4;
  const u16* Ag = A + (size_t)bm * 128 * K;
  const u16* Bg = B + (size_t)bn * 128 * K;
  f32x4 acc[4][4];
  #pragma unroll
  for (int i=0;i<4;++i)
    #pragma unroll
    for(int j=0;j<4;++j) acc[i][j] = (f32x4){0.f,0.f,0.f,0.f};

  for (int k0 = 0; k0 < K; k0 += 64){
    #pragma unroll
    for (int i = 0; i < 4; ++i){
      int c = i*256 + tid;
      int row = c >> 3, col8 = (c & 7) << 3;
      gld_lds16(Ag + (size_t)row*K + k0 + col8, &lA[c<<3]);
      gld_lds16(Bg + (size_t)row*K + k0 + col8, &lB[c<<3]);
    }
    __syncthreads();
    #pragma unroll
    for (int kk = 0; kk < 2; ++kk){
      short8 af[4], bfr[4];
      #pragma unroll
      for (int f = 0; f < 4; ++f)
        af[f] = *(const short8*)&lA[(wrow + f*16 + l15)*64 + kk*32 + lhi*8];
      #pragma unroll
      for (int g = 0; g < 4; ++g)
        bfr[g] = *(const short8*)&lB[(wcol + g*16 + l15)*64 + kk*32 + lhi*8];
      #pragma unroll
      for (int f = 0; f < 4; ++f)
        #pragma unroll
        for (int g = 0; g < 4; ++g)
          acc[f][g] = mfma16(af[f], bfr[g], acc[f][g]);
    }
    __syncthreads();
  }
  #pragma unroll
  for (int f = 0; f < 4; ++f){
    #pragma unroll
    for (int r = 0; r < 4; ++r){
      int m = bm*128 + wrow + f*16 + lhi*4 + r;
      #pragma unroll
      for (int g = 0; g < 4; ++g){
        int n = bn*128 + wcol + g*16 + l15;
        float v = acc[f][g][r];
        if (MODE == 0){
          v += bias1[n] + bias2[n];
          int d = n >> 9, gg = n & 511, b = m >> 9, s = m & 511;
          int sp = (d < 6) ? s : 511 - s;
          ((u16*)C)[(((size_t)(d*512 + sp)*16 + b) << 9) + gg] = f2bf(v);
        } else if (MODE == 1){
          v += bias1[n];
          v = 0.5f * v * (1.0f + erff(v * 0.70710678118f));
          ((u16*)C)[(size_t)m * N + n] = f2bf(v);
        } else {
          v += bias1[n];
          ((float*)C)[(size_t)m * N + n] = v;
        }
      }
    }
  }
}

// ---------------- LSTM scan: 12 WGs (one per direction), 512 threads ----------------
// Computes z^T[n][b] = W_hh[n,:]·h[b,:] via MFMA (A=W rows, B=h), C-in = x-projection.
// Wave w owns h-dims [w*16, w*16+16) across all 4 gate tiles -> c,h lane-local.
__global__ __launch_bounds__(512) void k_scan(const u16* __restrict__ whh, const u16* __restrict__ xp,
                       u16* __restrict__ cat)
{
  __shared__ __align__(16) u16 hb[16*136];   // h[b][128], rows padded to 136 (272B)
  __shared__ __align__(16) u16 zb[16*520];   // z_x[b][512], rows padded to 520 (1040B)
  int d = blockIdx.x;
  int tid = threadIdx.x, lane = tid & 63, w = tid >> 6;
  int l15 = lane & 15, lhi = lane >> 4;

  for (int i = tid; i < 16*136; i += 512) hb[i] = 0;

  // permanent W_hh fragments: [gate][k-step], rows = gate*128 + w*16 + l15
  short8 wf[4][4];
  #pragma unroll
  for (int g_ = 0; g_ < 4; ++g_)
    #pragma unroll
    for (int kk = 0; kk < 4; ++kk)
      wf[g_][kk] = *(const short8*)(whh + ((size_t)d*512 + g_*128 + w*16 + l15)*128 + kk*32 + lhi*8);

  // staging: per step slice = [16 b][512 n] bf16 = 16KB; thread loads 2x16B
  int srow = tid >> 5;            // batch row 0..15
  int sc16 = (tid & 31) << 4;     // ushort col offset
  const u16* xg = xp + ((size_t)d*512*16 + srow)*512 + sc16;
  int zoff = srow*520 + sc16;

  short8 p0 = *(const short8*)(xg);
  short8 p1 = *(const short8*)(xg + 8);
  *(short8*)&zb[zoff] = p0;
  *(short8*)&zb[zoff + 8] = p1;
  __syncthreads();

  float cr[4] = {0.f,0.f,0.f,0.f};
  int head = (d < 6) ? d : d - 6;
  int posoff = (d < 6) ? 0 : 128;
  size_t catbase = (size_t)head*256 + posoff + w*16 + lhi*4 + (size_t)l15*512*1536;

  for (int t = 0; t < 512; ++t){
    int tn = (t < 511) ? t + 1 : 511;
    short8 n0 = *(const short8*)(xg + (size_t)tn*8192);        // prefetch next z_x
    short8 n1 = *(const short8*)(xg + (size_t)tn*8192 + 8);

    short8 hf[4];
    #pragma unroll
    for (int kk = 0; kk < 4; ++kk)
      hf[kk] = *(const short8*)&hb[l15*136 + kk*32 + lhi*8];

    f32x4 acc[4];
    #pragma unroll
    for (int g_ = 0; g_ < 4; ++g_){
      ushort4 z4 = *(const ushort4*)&zb[l15*520 + g_*128 + w*16 + lhi*4];
      acc[g_] = (f32x4){ bf2f(z4.x), bf2f(z4.y), bf2f(z4.z), bf2f(z4.w) };
    }
    #pragma unroll
    for (int kk = 0; kk < 4; ++kk)
      #pragma unroll
      for (int g_ = 0; g_ < 4; ++g_)
        acc[g_] = mfma16(wf[g_][kk], hf[kk], acc[g_]);

    float hv[4];
    #pragma unroll
    for (int r = 0; r < 4; ++r){
      float fi = sigf(acc[0][r]);
      float ff = sigf(acc[1][r]);
      float fg = tanhf_(acc[2][r]);
      float fo = sigf(acc[3][r]);
      cr[r] = ff * cr[r] + fi * fg;
      hv[r] = fo * tanhf_(cr[r]);
    }
    ushort4 hp; hp.x=f2bf(hv[0]); hp.y=f2bf(hv[1]); hp.z=f2bf(hv[2]); hp.w=f2bf(hv[3]);

    int tout = (d < 6) ? t : 511 - t;
    *(ushort4*)(cat + catbase + (size_t)tout*1536) = hp;

    __syncthreads();                                   // all reads of hb/zb done
    *(ushort4*)&hb[l15*136 + w*16 + lhi*4] = hp;       // publish h_t
    *(short8*)&zb[zoff] = n0;                          // publish z_x(t+1)
    *(short8*)&zb[zoff + 8] = n1;
    __syncthreads();                                   // writes visible
  }
}

// ---------------- residual + LayerNorm ----------------
__global__ __launch_bounds__(256) void k_ln(const float* __restrict__ emb, const float* __restrict__ proj,
                     const float* __restrict__ gamma, const float* __restrict__ beta,
                     float* __restrict__ out)
{
  int row = blockIdx.x, tid = threadIdx.x;
  const float* pe = emb + (size_t)row * 768;
  const float* pp = proj + (size_t)row * 768;
  float v0 = pe[tid]     + pp[tid];
  float v1 = pe[tid+256] + pp[tid+256];
  float v2 = pe[tid+512] + pp[tid+512];
  float s = v0+v1+v2, s2 = v0*v0+v1*v1+v2*v2;
  #pragma unroll
  for (int o = 32; o > 0; o >>= 1){ s += __shfl_down(s, o); s2 += __shfl_down(s2, o); }
  __shared__ float rs[4], rq[4];
  int wv = tid >> 6;
  if ((tid & 63) == 0){ rs[wv] = s; rq[wv] = s2; }
  __syncthreads();
  s = rs[0]+rs[1]+rs[2]+rs[3];
  s2 = rq[0]+rq[1]+rq[2]+rq[3];
  float mu = s * (1.0f/768.0f);
  float var = s2 * (1.0f/768.0f) - mu*mu;
  float rr = rsqrtf(var + 1e-5f);
  float* po = out + (size_t)row * 768;
  po[tid]     = (v0-mu)*rr*gamma[tid]     + beta[tid];
  po[tid+256] = (v1-mu)*rr*gamma[tid+256] + beta[tid+256];
  po[tid+512] = (v2-mu)*rr*gamma[tid+512] + beta[tid+512];
}

extern "C" void kernel_launch(void* const* d_in, const int* in_sizes, int n_in,
                              void* d_out, int out_size, void* d_ws, size_t ws_size,
                              hipStream_t stream)
{
  const float* emb   = (const float*)d_in[0];
  const float* W_ih  = (const float*)d_in[1];
  const float* W_hh  = (const float*)d_in[2];
  const float* b_ih  = (const float*)d_in[3];
  const float* b_hh  = (const float*)d_in[4];
  const float* W_int = (const float*)d_in[5];
  const float* b_int = (const float*)d_in[6];
  const float* W_out = (const float*)d_in[7];
  const float* b_out = (const float*)d_in[8];
  const float* gamma = (const float*)d_in[9];
  const float* beta  = (const float*)d_in[10];
  float* out = (float*)d_out;

  char* ws = (char*)d_ws;
  u16* embb  = (u16*)(ws + 0);           // 12,582,912
  u16* wihb  = (u16*)(ws + 12582912);    //  9,437,184
  u16* whhb  = (u16*)(ws + 22020096);    //  1,572,864
  u16* wintb = (u16*)(ws + 23592960);    //  9,437,184
  u16* woutb = (u16*)(ws + 33030144);    //  4,718,592
  u16* catb  = (u16*)(ws + 37748736);    // 25,165,824
  u16* xp    = (u16*)(ws + 62914560);    // 100,663,296 (dead after scan)
  u16* interb= (u16*)(ws + 62914560);    // 50,331,648 (reuses xp)
  float* proj= (float*)(ws + 113246208); // 25,165,824 (reuses xp tail)

  auto cast = [&](const float* src, u16* dst, int n){
    int n4 = n >> 2;
    hipLaunchKernelGGL(k_cast, dim3((n4+255)/256), dim3(256), 0, stream, src, dst, n4);
  };
  cast(emb,   embb,  6291456);
  cast(W_ih,  wihb,  4718592);
  cast(W_hh,  whhb,   786432);
  cast(W_int, wintb, 4718592);
  cast(W_out, woutb, 2359296);

  // x-projection: [8192,768] x [6144,768]^T -> xp (bias, time-reversal baked in)
  hipLaunchKernelGGL((k_gemm<0>), dim3(3072), dim3(256), 0, stream,
                     embb, wihb, (void*)xp, b_ih, b_hh, 8192, 6144, 768);
  // sequential BiLSTM scan -> cat [16,512,1536] bf16
  hipLaunchKernelGGL(k_scan, dim3(12), dim3(512), 0, stream, whhb, xp, catb);
  // FFN up + gelu: [8192,1536] x [3072,1536]^T -> inter bf16
  hipLaunchKernelGGL((k_gemm<1>), dim3(1536), dim3(256), 0, stream,
                     catb, wintb, (void*)interb, b_int, nullptr, 8192, 3072, 1536);
  // FFN down: [8192,3072] x [768,3072]^T -> proj f32
  hipLaunchKernelGGL((k_gemm<2>), dim3(384), dim3(256), 0, stream,
                     interb, woutb, (void*)proj, b_out, nullptr, 8192, 768, 3072);
  // residual + LayerNorm
  hipLaunchKernelGGL(k_ln, dim3(8192), dim3(256), 0, stream, emb, proj, gamma, beta, out);
}

// Round 2
// 871.963 us; speedup vs baseline: 1.0073x; 1.0073x over previous
//
#include <hip/hip_runtime.h>

typedef __attribute__((ext_vector_type(4))) float f32x4;
typedef __attribute__((ext_vector_type(8))) short short8;
typedef unsigned short u16;
typedef unsigned int u32;

__device__ __forceinline__ u16 f2bf(float f){
  u32 x = __float_as_uint(f);
  u32 r = x + 0x7fffu + ((x >> 16) & 1u);
  return (u16)(r >> 16);
}
__device__ __forceinline__ float bf2f(u16 u){ return __uint_as_float(((u32)u) << 16); }
__device__ __forceinline__ float bfel(short8 v, int i){ return bf2f((u16)v[i]); }

__device__ __forceinline__ void gld_lds16(const u16* g, u16* l){
  __builtin_amdgcn_global_load_lds((const __attribute__((address_space(1))) void*)g,
                                   (__attribute__((address_space(3))) void*)l, 16, 0, 0);
}

__device__ __forceinline__ f32x4 mfma16(short8 a, short8 b, f32x4 c){
  return __builtin_amdgcn_mfma_f32_16x16x32_bf16(a, b, c, 0, 0, 0);
}

__device__ __forceinline__ float sigf(float x){
  return __builtin_amdgcn_rcpf(1.0f + __expf(-x));
}
__device__ __forceinline__ float tanhf_(float x){
  float e = __expf(2.0f * x);
  return 1.0f - 2.0f * __builtin_amdgcn_rcpf(e + 1.0f);
}

// ---------------- cast f32 -> bf16 ----------------
__global__ void k_cast(const float* __restrict__ in, u16* __restrict__ out, int n4){
  int i = blockIdx.x * 256 + threadIdx.x;
  if (i < n4){
    float4 v = ((const float4*)in)[i];
    ushort4 o; o.x=f2bf(v.x); o.y=f2bf(v.y); o.z=f2bf(v.z); o.w=f2bf(v.w);
    ((ushort4*)out)[i] = o;
  }
}

// ---------------- GEMM: A[M,K] row-major, B[N,K] row-major (B^T), bf16 in, f32 acc ----
// MODE 0: +bias1+bias2, store bf16 to xp[d][t][b][j*4+gate] (time-reversed for d>=6)
// MODE 1: +bias1, exact gelu, store bf16 row-major [M,N]
// MODE 2: +bias1, store f32 row-major [M,N]
template<int MODE>
__global__ __launch_bounds__(256) void k_gemm(const u16* __restrict__ A, const u16* __restrict__ B,
                       void* __restrict__ C, const float* __restrict__ bias1,
                       const float* __restrict__ bias2, int M, int N, int K)
{
  __shared__ __align__(16) u16 lA[128*64];
  __shared__ __align__(16) u16 lB[128*64];
  int nbm = M >> 7;
  int nwg = gridDim.x;
  int bid = blockIdx.x;
  int q = nwg >> 3;
  int swz = (bid & 7) * q + (bid >> 3);    // XCD-aware swizzle (nwg % 8 == 0 here)
  int bm = swz % nbm, bn = swz / nbm;
  int tid = threadIdx.x, lane = tid & 63;
  int wv = tid >> 6;
  int wrow = (wv & 1) << 6, wcol = (wv >> 1) << 6;
  int l15 = lane & 15, lhi = lane >> 4;
  const u16* Ag = A + (size_t)bm * 128 * K;
  const u16* Bg = B + (size_t)bn * 128 * K;
  f32x4 acc[4][4];
  #pragma unroll
  for (int i=0;i<4;++i)
    #pragma unroll
    for(int j=0;j<4;++j) acc[i][j] = (f32x4){0.f,0.f,0.f,0.f};

  for (int k0 = 0; k0 < K; k0 += 64){
    #pragma unroll
    for (int i = 0; i < 4; ++i){
      int c = i*256 + tid;
      int row = c >> 3, col8 = (c & 7) << 3;
      gld_lds16(Ag + (size_t)row*K + k0 + col8, &lA[c<<3]);
      gld_lds16(Bg + (size_t)row*K + k0 + col8, &lB[c<<3]);
    }
    __syncthreads();
    #pragma unroll
    for (int kk = 0; kk < 2; ++kk){
      short8 af[4], bfr[4];
      #pragma unroll
      for (int f = 0; f < 4; ++f)
        af[f] = *(const short8*)&lA[(wrow + f*16 + l15)*64 + kk*32 + lhi*8];
      #pragma unroll
      for (int g = 0; g < 4; ++g)
        bfr[g] = *(const short8*)&lB[(wcol + g*16 + l15)*64 + kk*32 + lhi*8];
      #pragma unroll
      for (int f = 0; f < 4; ++f)
        #pragma unroll
        for (int g = 0; g < 4; ++g)
          acc[f][g] = mfma16(af[f], bfr[g], acc[f][g]);
    }
    __syncthreads();
  }
  #pragma unroll
  for (int f = 0; f < 4; ++f){
    #pragma unroll
    for (int r = 0; r < 4; ++r){
      int m = bm*128 + wrow + f*16 + lhi*4 + r;
      #pragma unroll
      for (int g = 0; g < 4; ++g){
        int n = bn*128 + wcol + g*16 + l15;
        float v = acc[f][g][r];
        if (MODE == 0){
          v += bias1[n] + bias2[n];
          int dd = n >> 9, gg = n & 511, b = m >> 9, s = m & 511;
          int sp = (dd < 6) ? s : 511 - s;
          ((u16*)C)[(((size_t)(dd*512 + sp)*16 + b) << 9) + ((gg & 127) << 2) + (gg >> 7)] = f2bf(v);
        } else if (MODE == 1){
          v += bias1[n];
          v = 0.5f * v * (1.0f + erff(v * 0.70710678118f));
          ((u16*)C)[(size_t)m * N + n] = f2bf(v);
        } else {
          v += bias1[n];
          ((float*)C)[(size_t)m * N + n] = v;
        }
      }
    }
  }
}

// ---------------- LSTM scan: 12 WGs (one per direction), 512 threads ----------------
// z^T[n][b] = W_hh[n,:]·h[b,:] via MFMA (A=W rows, B=h rows=batch), C-in = x-proj
// loaded straight from global (gate-interleaved layout -> one 32B chunk per lane).
// Wave w owns dims [w*16, w*16+16) across all 4 gates -> c,h lane-local.
// Double-buffered h in LDS -> single raw barrier per step (no vmcnt drain).
__global__ __launch_bounds__(512) void k_scan(const u16* __restrict__ whh, const u16* __restrict__ xp,
                       u16* __restrict__ cat)
{
  __shared__ __align__(16) u16 hb[2][16*136];
  int d = blockIdx.x;
  int tid = threadIdx.x, lane = tid & 63, w = tid >> 6;
  int l15 = lane & 15, lhi = lane >> 4;

  u16* hbf = (u16*)hb;
  for (int i = tid; i < 2*16*136; i += 512) hbf[i] = 0;

  // permanent W_hh fragments: rows = d*512 + g*128 + w*16 + l15
  short8 wf[4][4];
  #pragma unroll
  for (int g = 0; g < 4; ++g)
    #pragma unroll
    for (int kk = 0; kk < 4; ++kk)
      wf[g][kk] = *(const short8*)(whh + ((size_t)d*512 + g*128 + w*16 + l15)*128 + kk*32 + lhi*8);

  // z_x: lane's 16 C-in values are contiguous 32B at [d][t][b=l15][(w*16+lhi*4)*4]
  const u16* zbase = xp + ((size_t)d*512*16 + l15)*512 + (w*16 + lhi*4)*4;
  short8 zA0 = *(const short8*)(zbase);
  short8 zA1 = *(const short8*)(zbase + 8);
  short8 zB0 = *(const short8*)(zbase + 8192);
  short8 zB1 = *(const short8*)(zbase + 8192 + 8);

  float cr0=0.f, cr1=0.f, cr2=0.f, cr3=0.f;
  int head = (d < 6) ? d : d - 6;
  int posoff = (d < 6) ? 0 : 128;
  size_t catlane = (size_t)head*256 + posoff + w*16 + lhi*4 + (size_t)l15*512*1536;
  int catoff = (d < 6) ? 0 : 511*1536;
  int catstep = (d < 6) ? 1536 : -1536;

  int rdo = l15*136;                  // B-frag row base (u16 idx)
  int wro = l15*136 + w*16 + lhi*4;   // h publish offset

  __syncthreads();

#define SCAN_STEP(T, RB, WB, Z0, Z1)                                            \
  {                                                                             \
    short8 hf0 = *(const short8*)&hb[RB][rdo + 0*32 + lhi*8];                   \
    short8 hf1 = *(const short8*)&hb[RB][rdo + 1*32 + lhi*8];                   \
    short8 hf2 = *(const short8*)&hb[RB][rdo + 2*32 + lhi*8];                   \
    short8 hf3 = *(const short8*)&hb[RB][rdo + 3*32 + lhi*8];                   \
    f32x4 a0 = { bfel(Z0,0), bfel(Z0,4), bfel(Z1,0), bfel(Z1,4) };              \
    f32x4 a1 = { bfel(Z0,1), bfel(Z0,5), bfel(Z1,1), bfel(Z1,5) };              \
    f32x4 a2 = { bfel(Z0,2), bfel(Z0,6), bfel(Z1,2), bfel(Z1,6) };              \
    f32x4 a3 = { bfel(Z0,3), bfel(Z0,7), bfel(Z1,3), bfel(Z1,7) };              \
    int t2 = (T) + 2; if (t2 > 511) t2 = 511;                                   \
    Z0 = *(const short8*)(zbase + (size_t)t2*8192);                             \
    Z1 = *(const short8*)(zbase + (size_t)t2*8192 + 8);                         \
    a0 = mfma16(wf[0][0], hf0, a0); a1 = mfma16(wf[1][0], hf0, a1);             \
    a2 = mfma16(wf[2][0], hf0, a2); a3 = mfma16(wf[3][0], hf0, a3);             \
    a0 = mfma16(wf[0][1], hf1, a0); a1 = mfma16(wf[1][1], hf1, a1);             \
    a2 = mfma16(wf[2][1], hf1, a2); a3 = mfma16(wf[3][1], hf1, a3);             \
    a0 = mfma16(wf[0][2], hf2, a0); a1 = mfma16(wf[1][2], hf2, a1);             \
    a2 = mfma16(wf[2][2], hf2, a2); a3 = mfma16(wf[3][2], hf2, a3);             \
    a0 = mfma16(wf[0][3], hf3, a0); a1 = mfma16(wf[1][3], hf3, a1);             \
    a2 = mfma16(wf[2][3], hf3, a2); a3 = mfma16(wf[3][3], hf3, a3);             \
    float hv0, hv1, hv2, hv3;                                                   \
    { float fi=sigf(a0[0]), ff=sigf(a1[0]), tg=tanhf_(a2[0]), fo=sigf(a3[0]);   \
      cr0 = ff*cr0 + fi*tg; hv0 = fo*tanhf_(cr0); }                             \
    { float fi=sigf(a0[1]), ff=sigf(a1[1]), tg=tanhf_(a2[1]), fo=sigf(a3[1]);   \
      cr1 = ff*cr1 + fi*tg; hv1 = fo*tanhf_(cr1); }                             \
    { float fi=sigf(a0[2]), ff=sigf(a1[2]), tg=tanhf_(a2[2]), fo=sigf(a3[2]);   \
      cr2 = ff*cr2 + fi*tg; hv2 = fo*tanhf_(cr2); }                             \
    { float fi=sigf(a0[3]), ff=sigf(a1[3]), tg=tanhf_(a2[3]), fo=sigf(a3[3]);   \
      cr3 = ff*cr3 + fi*tg; hv3 = fo*tanhf_(cr3); }                             \
    ushort4 hp; hp.x=f2bf(hv0); hp.y=f2bf(hv1); hp.z=f2bf(hv2); hp.w=f2bf(hv3); \
    *(ushort4*)(cat + catlane + catoff) = hp;                                   \
    catoff += catstep;                                                          \
    *(ushort4*)&hb[WB][wro] = hp;                                               \
    asm volatile("s_waitcnt lgkmcnt(0)" ::: "memory");                          \
    __builtin_amdgcn_s_barrier();                                               \
  }

  for (int t = 0; t < 512; t += 2){
    SCAN_STEP(t,   0, 1, zA0, zA1)
    SCAN_STEP(t+1, 1, 0, zB0, zB1)
  }
#undef SCAN_STEP
}

// ---------------- residual + LayerNorm ----------------
__global__ __launch_bounds__(256) void k_ln(const float* __restrict__ emb, const float* __restrict__ proj,
                     const float* __restrict__ gamma, const float* __restrict__ beta,
                     float* __restrict__ out)
{
  int row = blockIdx.x, tid = threadIdx.x;
  const float* pe = emb + (size_t)row * 768;
  const float* pp = proj + (size_t)row * 768;
  float v0 = pe[tid]     + pp[tid];
  float v1 = pe[tid+256] + pp[tid+256];
  float v2 = pe[tid+512] + pp[tid+512];
  float s = v0+v1+v2, s2 = v0*v0+v1*v1+v2*v2;
  #pragma unroll
  for (int o = 32; o > 0; o >>= 1){ s += __shfl_down(s, o); s2 += __shfl_down(s2, o); }
  __shared__ float rs[4], rq[4];
  int wv = tid >> 6;
  if ((tid & 63) == 0){ rs[wv] = s; rq[wv] = s2; }
  __syncthreads();
  s = rs[0]+rs[1]+rs[2]+rs[3];
  s2 = rq[0]+rq[1]+rq[2]+rq[3];
  float mu = s * (1.0f/768.0f);
  float var = s2 * (1.0f/768.0f) - mu*mu;
  float rr = rsqrtf(var + 1e-5f);
  float* po = out + (size_t)row * 768;
  po[tid]     = (v0-mu)*rr*gamma[tid]     + beta[tid];
  po[tid+256] = (v1-mu)*rr*gamma[tid+256] + beta[tid+256];
  po[tid+512] = (v2-mu)*rr*gamma[tid+512] + beta[tid+512];
}

extern "C" void kernel_launch(void* const* d_in, const int* in_sizes, int n_in,
                              void* d_out, int out_size, void* d_ws, size_t ws_size,
                              hipStream_t stream)
{
  const float* emb   = (const float*)d_in[0];
  const float* W_ih  = (const float*)d_in[1];
  const float* W_hh  = (const float*)d_in[2];
  const float* b_ih  = (const float*)d_in[3];
  const float* b_hh  = (const float*)d_in[4];
  const float* W_int = (const float*)d_in[5];
  const float* b_int = (const float*)d_in[6];
  const float* W_out = (const float*)d_in[7];
  const float* b_out = (const float*)d_in[8];
  const float* gamma = (const float*)d_in[9];
  const float* beta  = (const float*)d_in[10];
  float* out = (float*)d_out;

  char* ws = (char*)d_ws;
  u16* embb  = (u16*)(ws + 0);           // 12,582,912
  u16* wihb  = (u16*)(ws + 12582912);    //  9,437,184
  u16* whhb  = (u16*)(ws + 22020096);    //  1,572,864
  u16* wintb = (u16*)(ws + 23592960);    //  9,437,184
  u16* woutb = (u16*)(ws + 33030144);    //  4,718,592
  u16* catb  = (u16*)(ws + 37748736);    // 25,165,824
  u16* xp    = (u16*)(ws + 62914560);    // 100,663,296 (dead after scan)
  u16* interb= (u16*)(ws + 62914560);    // 50,331,648 (reuses xp)
  float* proj= (float*)(ws + 113246208); // 25,165,824 (reuses xp tail)

  auto cast = [&](const float* src, u16* dst, int n){
    int n4 = n >> 2;
    hipLaunchKernelGGL(k_cast, dim3((n4+255)/256), dim3(256), 0, stream, src, dst, n4);
  };
  cast(emb,   embb,  6291456);
  cast(W_ih,  wihb,  4718592);
  cast(W_hh,  whhb,   786432);
  cast(W_int, wintb, 4718592);
  cast(W_out, woutb, 2359296);

  // x-projection: [8192,768] x [6144,768]^T -> xp (bias, time-reversal, gate-interleave baked in)
  hipLaunchKernelGGL((k_gemm<0>), dim3(3072), dim3(256), 0, stream,
                     embb, wihb, (void*)xp, b_ih, b_hh, 8192, 6144, 768);
  // sequential BiLSTM scan -> cat [16,512,1536] bf16
  hipLaunchKernelGGL(k_scan, dim3(12), dim3(512), 0, stream, whhb, xp, catb);
  // FFN up + gelu: [8192,1536] x [3072,1536]^T -> inter bf16
  hipLaunchKernelGGL((k_gemm<1>), dim3(1536), dim3(256), 0, stream,
                     catb, wintb, (void*)interb, b_int, nullptr, 8192, 3072, 1536);
  // FFN down: [8192,3072] x [768,3072]^T -> proj f32
  hipLaunchKernelGGL((k_gemm<2>), dim3(384), dim3(256), 0, stream,
                     interb, woutb, (void*)proj, b_out, nullptr, 8192, 768, 3072);
  // residual + LayerNorm
  hipLaunchKernelGGL(k_ln, dim3(8192), dim3(256), 0, stream, emb, proj, gamma, beta, out);
}

// Round 3
// 649.392 us; speedup vs baseline: 1.3525x; 1.3427x over previous
//
#include <hip/hip_runtime.h>

typedef __attribute__((ext_vector_type(4))) float f32x4;
typedef __attribute__((ext_vector_type(8))) short short8;
typedef unsigned short u16;
typedef unsigned int u32;

__device__ __forceinline__ u16 f2bf(float f){
  u32 x = __float_as_uint(f);
  u32 r = x + 0x7fffu + ((x >> 16) & 1u);
  return (u16)(r >> 16);
}
__device__ __forceinline__ float bf2f(u16 u){ return __uint_as_float(((u32)u) << 16); }

__device__ __forceinline__ void gld_lds16(const u16* g, u16* l){
  __builtin_amdgcn_global_load_lds((const __attribute__((address_space(1))) void*)g,
                                   (__attribute__((address_space(3))) void*)l, 16, 0, 0);
}

__device__ __forceinline__ f32x4 mfma16(short8 a, short8 b, f32x4 c){
  return __builtin_amdgcn_mfma_f32_16x16x32_bf16(a, b, c, 0, 0, 0);
}

__device__ __forceinline__ float sigf(float x){
  return __builtin_amdgcn_rcpf(1.0f + __expf(-x));
}
__device__ __forceinline__ float tanhf_(float x){
  float e = __expf(2.0f * x);
  return 1.0f - 2.0f * __builtin_amdgcn_rcpf(e + 1.0f);
}

// ---------------- cast f32 -> bf16 ----------------
__global__ void k_cast(const float* __restrict__ in, u16* __restrict__ out, int n4){
  int i = blockIdx.x * 256 + threadIdx.x;
  if (i < n4){
    float4 v = ((const float4*)in)[i];
    ushort4 o; o.x=f2bf(v.x); o.y=f2bf(v.y); o.z=f2bf(v.z); o.w=f2bf(v.w);
    ((ushort4*)out)[i] = o;
  }
}

// ---------------- GEMM: A[M,K] row-major, B[N,K] row-major (B^T), bf16 in, f32 acc ----
// MODE 0: +bias1+bias2, store bf16 to xp[d][t][b][dim*4+gate] (time-reversed for d>=6)
// MODE 1: +bias1, exact gelu, store bf16 row-major [M,N]
// MODE 2: +bias1, store f32 row-major [M,N]
template<int MODE>
__global__ __launch_bounds__(256) void k_gemm(const u16* __restrict__ A, const u16* __restrict__ B,
                       void* __restrict__ C, const float* __restrict__ bias1,
                       const float* __restrict__ bias2, int M, int N, int K)
{
  __shared__ __align__(16) u16 lA[128*64];
  __shared__ __align__(16) u16 lB[128*64];
  int nbm = M >> 7;
  int nwg = gridDim.x;
  int bid = blockIdx.x;
  int q = nwg >> 3;
  int swz = (bid & 7) * q + (bid >> 3);    // XCD-aware swizzle (nwg % 8 == 0 here)
  int bm = swz % nbm, bn = swz / nbm;
  int tid = threadIdx.x, lane = tid & 63;
  int wv = tid >> 6;
  int wrow = (wv & 1) << 6, wcol = (wv >> 1) << 6;
  int l15 = lane & 15, lhi = lane >> 4;
  const u16* Ag = A + (size_t)bm * 128 * K;
  const u16* Bg = B + (size_t)bn * 128 * K;
  f32x4 acc[4][4];
  #pragma unroll
  for (int i=0;i<4;++i)
    #pragma unroll
    for(int j=0;j<4;++j) acc[i][j] = (f32x4){0.f,0.f,0.f,0.f};

  for (int k0 = 0; k0 < K; k0 += 64){
    #pragma unroll
    for (int i = 0; i < 4; ++i){
      int c = i*256 + tid;
      int row = c >> 3, col8 = (c & 7) << 3;
      gld_lds16(Ag + (size_t)row*K + k0 + col8, &lA[c<<3]);
      gld_lds16(Bg + (size_t)row*K + k0 + col8, &lB[c<<3]);
    }
    __syncthreads();
    #pragma unroll
    for (int kk = 0; kk < 2; ++kk){
      short8 af[4], bfr[4];
      #pragma unroll
      for (int f = 0; f < 4; ++f)
        af[f] = *(const short8*)&lA[(wrow + f*16 + l15)*64 + kk*32 + lhi*8];
      #pragma unroll
      for (int g = 0; g < 4; ++g)
        bfr[g] = *(const short8*)&lB[(wcol + g*16 + l15)*64 + kk*32 + lhi*8];
      #pragma unroll
      for (int f = 0; f < 4; ++f)
        #pragma unroll
        for (int g = 0; g < 4; ++g)
          acc[f][g] = mfma16(af[f], bfr[g], acc[f][g]);
    }
    __syncthreads();
  }
  #pragma unroll
  for (int f = 0; f < 4; ++f){
    #pragma unroll
    for (int r = 0; r < 4; ++r){
      int m = bm*128 + wrow + f*16 + lhi*4 + r;
      #pragma unroll
      for (int g = 0; g < 4; ++g){
        int n = bn*128 + wcol + g*16 + l15;
        float v = acc[f][g][r];
        if (MODE == 0){
          v += bias1[n] + bias2[n];
          int dd = n >> 9, gg = n & 511, b = m >> 9, s = m & 511;
          int sp = (dd < 6) ? s : 511 - s;
          ((u16*)C)[(((size_t)(dd*512 + sp)*16 + b) << 9) + ((gg & 127) << 2) + (gg >> 7)] = f2bf(v);
        } else if (MODE == 1){
          v += bias1[n];
          v = 0.5f * v * (1.0f + erff(v * 0.70710678118f));
          ((u16*)C)[(size_t)m * N + n] = f2bf(v);
        } else {
          v += bias1[n];
          ((float*)C)[(size_t)m * N + n] = v;
        }
      }
    }
  }
}

// ---------------- LSTM scan: 48 WGs (dir x 4 batch-groups), 512 threads ----------------
// Replica-row MFMA: A = h-replicas (row m <-> batch m>>2), B = W rows (cols = dims),
// one C tile per gate. Lane (w,l15,lhi) reg0 = gate value for (dim w*16+l15, batch lhi)
// -> exactly ONE h-element per lane, static register index, no shuffles.
// C rows 1-3 are replicas: their accs accumulate junk (finite), never read.
__global__ __launch_bounds__(512) void k_scan(const u16* __restrict__ whh, const u16* __restrict__ xp,
                       u16* __restrict__ cat)
{
  __shared__ __align__(16) u16 hb[2][4*144];   // h[batch][dim], rows padded to 144 u16
  int bid = blockIdx.x;
  int d = bid >> 2, bg = bid & 3;
  int tid = threadIdx.x, lane = tid & 63, w = tid >> 6;
  int l15 = lane & 15, lhi = lane >> 4;

  u16* hbf = (u16*)hb;
  for (int i = tid; i < 2*4*144; i += 512) hbf[i] = 0;

  // W_hh fragments: tile tau = gate tau; Y-frag row (=col n) = l15 -> dim w*16+l15
  short8 wf[4][4];
  #pragma unroll
  for (int g = 0; g < 4; ++g)
    #pragma unroll
    for (int kk = 0; kk < 4; ++kk)
      wf[g][kk] = *(const short8*)(whh + ((size_t)d*512 + g*128 + w*16 + l15)*128 + kk*32 + lhi*8);

  // z_x: lane loads gates 0-3 of (dim w*16+l15, batch bg*4+lhi): one ushort4 (8B)
  const u16* zbase = xp + ((size_t)(d*512)*16 + bg*4 + lhi)*512 + (w*16 + l15)*4;
  ushort4 Z0 = *(const ushort4*)(zbase);
  ushort4 Z1 = *(const ushort4*)(zbase + 8192);
  ushort4 Z2 = *(const ushort4*)(zbase + 16384);
  ushort4 Z3 = *(const ushort4*)(zbase + 24576);

  f32x4 a0 = {0.f,0.f,0.f,0.f}, a1 = a0, a2 = a0, a3 = a0;
  float cr = 0.f;
  int head = (d < 6) ? d : d - 6;
  int posoff = (d < 6) ? 0 : 128;
  size_t catlane = (size_t)(bg*4 + lhi)*512*1536 + head*256 + posoff + w*16 + l15;
  int catoff = (d < 6) ? 0 : 511*1536;
  int catstep = (d < 6) ? 1536 : -1536;

  int hrd = (l15 >> 2)*144 + lhi*8;   // A-frag: h[batch l15>>2], k-slice lhi*8
  int hwr = lhi*144 + w*16 + l15;     // publish h(dim, batch lhi)

  __syncthreads();

#define SCAN_STEP(T, RB, WB, ZS)                                               \
  {                                                                            \
    short8 hf0 = *(const short8*)&hb[RB][hrd + 0*32];                          \
    short8 hf1 = *(const short8*)&hb[RB][hrd + 1*32];                          \
    short8 hf2 = *(const short8*)&hb[RB][hrd + 2*32];                          \
    short8 hf3 = *(const short8*)&hb[RB][hrd + 3*32];                          \
    a0[0] = bf2f(ZS.x); a1[0] = bf2f(ZS.y);                                    \
    a2[0] = bf2f(ZS.z); a3[0] = bf2f(ZS.w);                                    \
    int t4 = (T) + 4; if (t4 > 511) t4 = 511;                                  \
    ZS = *(const ushort4*)(zbase + (size_t)t4*8192);                           \
    a0 = mfma16(hf0, wf[0][0], a0); a1 = mfma16(hf0, wf[1][0], a1);            \
    a2 = mfma16(hf0, wf[2][0], a2); a3 = mfma16(hf0, wf[3][0], a3);            \
    a0 = mfma16(hf1, wf[0][1], a0); a1 = mfma16(hf1, wf[1][1], a1);            \
    a2 = mfma16(hf1, wf[2][1], a2); a3 = mfma16(hf1, wf[3][1], a3);            \
    a0 = mfma16(hf2, wf[0][2], a0); a1 = mfma16(hf2, wf[1][2], a1);            \
    a2 = mfma16(hf2, wf[2][2], a2); a3 = mfma16(hf2, wf[3][2], a3);            \
    a0 = mfma16(hf3, wf[0][3], a0); a1 = mfma16(hf3, wf[1][3], a1);            \
    a2 = mfma16(hf3, wf[2][3], a2); a3 = mfma16(hf3, wf[3][3], a3);            \
    float fi = sigf(a0[0]), ff = sigf(a1[0]);                                  \
    float tg = tanhf_(a2[0]), fo = sigf(a3[0]);                                \
    cr = ff*cr + fi*tg;                                                        \
    u16 hp = f2bf(fo * tanhf_(cr));                                            \
    cat[catlane + catoff] = hp;                                                \
    catoff += catstep;                                                         \
    hb[WB][hwr] = hp;                                                          \
    asm volatile("s_waitcnt lgkmcnt(0)" ::: "memory");                         \
    __builtin_amdgcn_s_barrier();                                              \
  }

  for (int t = 0; t < 512; t += 4){
    SCAN_STEP(t,   0, 1, Z0)
    SCAN_STEP(t+1, 1, 0, Z1)
    SCAN_STEP(t+2, 0, 1, Z2)
    SCAN_STEP(t+3, 1, 0, Z3)
  }
#undef SCAN_STEP
}

// ---------------- residual + LayerNorm ----------------
__global__ __launch_bounds__(256) void k_ln(const float* __restrict__ emb, const float* __restrict__ proj,
                     const float* __restrict__ gamma, const float* __restrict__ beta,
                     float* __restrict__ out)
{
  int row = blockIdx.x, tid = threadIdx.x;
  const float* pe = emb + (size_t)row * 768;
  const float* pp = proj + (size_t)row * 768;
  float v0 = pe[tid]     + pp[tid];
  float v1 = pe[tid+256] + pp[tid+256];
  float v2 = pe[tid+512] + pp[tid+512];
  float s = v0+v1+v2, s2 = v0*v0+v1*v1+v2*v2;
  #pragma unroll
  for (int o = 32; o > 0; o >>= 1){ s += __shfl_down(s, o); s2 += __shfl_down(s2, o); }
  __shared__ float rs[4], rq[4];
  int wv = tid >> 6;
  if ((tid & 63) == 0){ rs[wv] = s; rq[wv] = s2; }
  __syncthreads();
  s = rs[0]+rs[1]+rs[2]+rs[3];
  s2 = rq[0]+rq[1]+rq[2]+rq[3];
  float mu = s * (1.0f/768.0f);
  float var = s2 * (1.0f/768.0f) - mu*mu;
  float rr = rsqrtf(var + 1e-5f);
  float* po = out + (size_t)row * 768;
  po[tid]     = (v0-mu)*rr*gamma[tid]     + beta[tid];
  po[tid+256] = (v1-mu)*rr*gamma[tid+256] + beta[tid+256];
  po[tid+512] = (v2-mu)*rr*gamma[tid+512] + beta[tid+512];
}

extern "C" void kernel_launch(void* const* d_in, const int* in_sizes, int n_in,
                              void* d_out, int out_size, void* d_ws, size_t ws_size,
                              hipStream_t stream)
{
  const float* emb   = (const float*)d_in[0];
  const float* W_ih  = (const float*)d_in[1];
  const float* W_hh  = (const float*)d_in[2];
  const float* b_ih  = (const float*)d_in[3];
  const float* b_hh  = (const float*)d_in[4];
  const float* W_int = (const float*)d_in[5];
  const float* b_int = (const float*)d_in[6];
  const float* W_out = (const float*)d_in[7];
  const float* b_out = (const float*)d_in[8];
  const float* gamma = (const float*)d_in[9];
  const float* beta  = (const float*)d_in[10];
  float* out = (float*)d_out;

  char* ws = (char*)d_ws;
  u16* embb  = (u16*)(ws + 0);           // 12,582,912
  u16* wihb  = (u16*)(ws + 12582912);    //  9,437,184
  u16* whhb  = (u16*)(ws + 22020096);    //  1,572,864
  u16* wintb = (u16*)(ws + 23592960);    //  9,437,184
  u16* woutb = (u16*)(ws + 33030144);    //  4,718,592
  u16* catb  = (u16*)(ws + 37748736);    // 25,165,824
  u16* xp    = (u16*)(ws + 62914560);    // 100,663,296 (dead after scan)
  u16* interb= (u16*)(ws + 62914560);    // 50,331,648 (reuses xp)
  float* proj= (float*)(ws + 113246208); // 25,165,824 (reuses xp tail)

  auto cast = [&](const float* src, u16* dst, int n){
    int n4 = n >> 2;
    hipLaunchKernelGGL(k_cast, dim3((n4+255)/256), dim3(256), 0, stream, src, dst, n4);
  };
  cast(emb,   embb,  6291456);
  cast(W_ih,  wihb,  4718592);
  cast(W_hh,  whhb,   786432);
  cast(W_int, wintb, 4718592);
  cast(W_out, woutb, 2359296);

  // x-projection: [8192,768] x [6144,768]^T -> xp (bias, time-reversal, gate-interleave baked in)
  hipLaunchKernelGGL((k_gemm<0>), dim3(3072), dim3(256), 0, stream,
                     embb, wihb, (void*)xp, b_ih, b_hh, 8192, 6144, 768);
  // sequential BiLSTM scan -> cat [16,512,1536] bf16
  hipLaunchKernelGGL(k_scan, dim3(48), dim3(512), 0, stream, whhb, xp, catb);
  // FFN up + gelu: [8192,1536] x [3072,1536]^T -> inter bf16
  hipLaunchKernelGGL((k_gemm<1>), dim3(1536), dim3(256), 0, stream,
                     catb, wintb, (void*)interb, b_int, nullptr, 8192, 3072, 1536);
  // FFN down: [8192,3072] x [768,3072]^T -> proj f32
  hipLaunchKernelGGL((k_gemm<2>), dim3(384), dim3(256), 0, stream,
                     interb, woutb, (void*)proj, b_out, nullptr, 8192, 768, 3072);
  // residual + LayerNorm
  hipLaunchKernelGGL(k_ln, dim3(8192), dim3(256), 0, stream, emb, proj, gamma, beta, out);
}

// Round 5
// 621.475 us; speedup vs baseline: 1.4133x; 1.0449x over previous
//
#include <hip/hip_runtime.h>

typedef __attribute__((ext_vector_type(4))) float f32x4;
typedef __attribute__((ext_vector_type(8))) short short8;
typedef unsigned short u16;
typedef unsigned int u32;

__device__ __forceinline__ u16 f2bf(float f){
  u32 x = __float_as_uint(f);
  u32 r = x + 0x7fffu + ((x >> 16) & 1u);
  return (u16)(r >> 16);
}
__device__ __forceinline__ float bf2f(u16 u){ return __uint_as_float(((u32)u) << 16); }
__device__ __forceinline__ float bf2f32(u32 u){ return __uint_as_float(u << 16); }

__device__ __forceinline__ void gld_lds16(const u16* g, u16* l){
  __builtin_amdgcn_global_load_lds((const __attribute__((address_space(1))) void*)g,
                                   (__attribute__((address_space(3))) void*)l, 16, 0, 0);
}

__device__ __forceinline__ f32x4 mfma16(short8 a, short8 b, f32x4 c){
  return __builtin_amdgcn_mfma_f32_16x16x32_bf16(a, b, c, 0, 0, 0);
}

__device__ __forceinline__ float sigf(float x){
  return __builtin_amdgcn_rcpf(1.0f + __expf(-x));
}
__device__ __forceinline__ float tanhf_(float x){
  float e = __expf(2.0f * x);
  return 1.0f - 2.0f * __builtin_amdgcn_rcpf(e + 1.0f);
}

// ---------------- cast f32 -> bf16 ----------------
__global__ void k_cast(const float* __restrict__ in, u16* __restrict__ out, int n4){
  int i = blockIdx.x * 256 + threadIdx.x;
  if (i < n4){
    float4 v = ((const float4*)in)[i];
    ushort4 o; o.x=f2bf(v.x); o.y=f2bf(v.y); o.z=f2bf(v.z); o.w=f2bf(v.w);
    ((ushort4*)out)[i] = o;
  }
}

// ---------------- GEMM: A[M,K] row-major (stride lda), B[N,K] row-major (stride lda) ----
// MODE 0: +bias1+bias2, store bf16 row-major [M,N]
// MODE 1: +bias1, exact gelu, store bf16 row-major [M,N]
// MODE 2: split-K by grid half; +bias1 (half 0 only); half0 -> C (f32), half1 -> C2 (f32)
template<int MODE>
__global__ __launch_bounds__(256) void k_gemm(const u16* __restrict__ A, const u16* __restrict__ B,
                       void* __restrict__ C, void* __restrict__ C2,
                       const float* __restrict__ bias1, const float* __restrict__ bias2,
                       int M, int N, int K, int lda)
{
  __shared__ __align__(16) u16 lA[128*64];
  __shared__ __align__(16) u16 lB[128*64];
  int nwg = gridDim.x;
  int bid = blockIdx.x;
  int half = 0;
  if (MODE == 2){
    int h2 = nwg >> 1;
    half = (bid >= h2) ? 1 : 0;
    bid -= half ? h2 : 0;
    nwg = h2;
  }
  int koff = half * K;
  int nbm = M >> 7;
  int q = nwg >> 3;
  int swz = (bid & 7) * q + (bid >> 3);    // XCD-aware swizzle (nwg % 8 == 0 here)
  int bm = swz % nbm, bn = swz / nbm;
  int tid = threadIdx.x, lane = tid & 63;
  int wv = tid >> 6;
  int wrow = (wv & 1) << 6, wcol = (wv >> 1) << 6;
  int l15 = lane & 15, lhi = lane >> 4;
  const u16* Ag = A + (size_t)bm * 128 * lda + koff;
  const u16* Bg = B + (size_t)bn * 128 * lda + koff;
  f32x4 acc[4][4];
  #pragma unroll
  for (int i=0;i<4;++i)
    #pragma unroll
    for(int j=0;j<4;++j) acc[i][j] = (f32x4){0.f,0.f,0.f,0.f};

  for (int k0 = 0; k0 < K; k0 += 64){
    #pragma unroll
    for (int i = 0; i < 4; ++i){
      int c = i*256 + tid;
      int row = c >> 3, col8 = (c & 7) << 3;
      gld_lds16(Ag + (size_t)row*lda + k0 + col8, &lA[c<<3]);
      gld_lds16(Bg + (size_t)row*lda + k0 + col8, &lB[c<<3]);
    }
    __syncthreads();
    #pragma unroll
    for (int kk = 0; kk < 2; ++kk){
      short8 af[4], bfr[4];
      #pragma unroll
      for (int f = 0; f < 4; ++f)
        af[f] = *(const short8*)&lA[(wrow + f*16 + l15)*64 + kk*32 + lhi*8];
      #pragma unroll
      for (int g = 0; g < 4; ++g)
        bfr[g] = *(const short8*)&lB[(wcol + g*16 + l15)*64 + kk*32 + lhi*8];
      #pragma unroll
      for (int f = 0; f < 4; ++f)
        #pragma unroll
        for (int g = 0; g < 4; ++g)
          acc[f][g] = mfma16(af[f], bfr[g], acc[f][g]);
    }
    __syncthreads();
  }
  #pragma unroll
  for (int f = 0; f < 4; ++f){
    #pragma unroll
    for (int r = 0; r < 4; ++r){
      int m = bm*128 + wrow + f*16 + lhi*4 + r;
      #pragma unroll
      for (int g = 0; g < 4; ++g){
        int n = bn*128 + wcol + g*16 + l15;
        float v = acc[f][g][r];
        if (MODE == 0){
          v += bias1[n] + bias2[n];
          ((u16*)C)[(size_t)m * N + n] = f2bf(v);
        } else if (MODE == 1){
          v += bias1[n];
          v = 0.5f * v * (1.0f + erff(v * 0.70710678118f));
          ((u16*)C)[(size_t)m * N + n] = f2bf(v);
        } else {
          if (!half) v += bias1[n];
          ((float*)(half ? C2 : C))[(size_t)m * N + n] = v;
        }
      }
    }
  }
}

// ---------------- LSTM scan: 48 WGs (dir x 4 batch-groups), 512 threads ----------------
// Replica-row MFMA: A = h-replicas (row m <-> batch m>>2), B = W rows (cols = dims).
// Lane (w,l15,lhi) reg0 = gate value for (dim w*16+l15, batch bg*4+lhi).
// Per-gate K=128 chain split lo(k0,k1)/hi(k2,k3) -> depth 2 + add.
// z_x read straight from row-major xp (4 scalar u16 loads, 4-step prefetch).
__global__ __launch_bounds__(512) void k_scan(const u16* __restrict__ whh, const u16* __restrict__ xp,
                       u16* __restrict__ cat)
{
  __shared__ __align__(16) u16 hb[2][4*144];   // h[batch][dim], rows padded to 144 u16
  int bid = blockIdx.x;
  int d = bid >> 2, bg = bid & 3;
  int tid = threadIdx.x, lane = tid & 63, w = tid >> 6;
  int l15 = lane & 15, lhi = lane >> 4;

  u16* hbf = (u16*)hb;
  for (int i = tid; i < 2*4*144; i += 512) hbf[i] = 0;

  short8 wf[4][4];
  #pragma unroll
  for (int g = 0; g < 4; ++g)
    #pragma unroll
    for (int kk = 0; kk < 4; ++kk)
      wf[g][kk] = *(const short8*)(whh + ((size_t)d*512 + g*128 + w*16 + l15)*128 + kk*32 + lhi*8);

  int b = bg*4 + lhi;
  int dim = w*16 + l15;
  bool fwd = (d < 6);
  const u16* zrow = xp + (size_t)b*512*6144 + d*512 + dim;  // + s*6144 + gate*128

  u32 Zi[4], Zf[4], Zg[4], Zo[4];
  #pragma unroll
  for (int j = 0; j < 4; ++j){
    int s = fwd ? j : 511 - j;
    const u16* p = zrow + (size_t)s*6144;
    Zi[j] = p[0]; Zf[j] = p[128]; Zg[j] = p[256]; Zo[j] = p[384];
  }

  f32x4 alo0={0.f,0.f,0.f,0.f}, alo1=alo0, alo2=alo0, alo3=alo0;
  f32x4 ahi0=alo0, ahi1=alo0, ahi2=alo0, ahi3=alo0;
  float cr = 0.f;
  int head = fwd ? d : d - 6;
  int posoff = fwd ? 0 : 128;
  size_t catlane = (size_t)b*512*1536 + head*256 + posoff + dim;
  int catoff = fwd ? 0 : 511*1536;
  int catstep = fwd ? 1536 : -1536;

  int hrd = (l15 >> 2)*144 + lhi*8;   // A-frag: h[batch l15>>2], k-slice lhi*8
  int hwr = lhi*144 + dim;            // publish h(dim, batch lhi)

  __syncthreads();

#define SCAN_STEP(T, RB, WB, S)                                                \
  {                                                                            \
    short8 hf0 = *(const short8*)&hb[RB][hrd + 0*32];                          \
    short8 hf1 = *(const short8*)&hb[RB][hrd + 1*32];                          \
    short8 hf2 = *(const short8*)&hb[RB][hrd + 2*32];                          \
    short8 hf3 = *(const short8*)&hb[RB][hrd + 3*32];                          \
    alo0[0] = bf2f32(Zi[S]); ahi0[0] = 0.f;                                    \
    alo1[0] = bf2f32(Zf[S]); ahi1[0] = 0.f;                                    \
    alo2[0] = bf2f32(Zg[S]); ahi2[0] = 0.f;                                    \
    alo3[0] = bf2f32(Zo[S]); ahi3[0] = 0.f;                                    \
    int t4 = (T) + 4; if (t4 > 511) t4 = 511;                                  \
    int s4 = fwd ? t4 : 511 - t4;                                              \
    const u16* pf = zrow + (size_t)s4*6144;                                    \
    Zi[S] = pf[0]; Zf[S] = pf[128]; Zg[S] = pf[256]; Zo[S] = pf[384];          \
    alo0 = mfma16(hf0, wf[0][0], alo0); alo1 = mfma16(hf0, wf[1][0], alo1);    \
    alo2 = mfma16(hf0, wf[2][0], alo2); alo3 = mfma16(hf0, wf[3][0], alo3);    \
    ahi0 = mfma16(hf2, wf[0][2], ahi0); ahi1 = mfma16(hf2, wf[1][2], ahi1);    \
    ahi2 = mfma16(hf2, wf[2][2], ahi2); ahi3 = mfma16(hf2, wf[3][2], ahi3);    \
    alo0 = mfma16(hf1, wf[0][1], alo0); alo1 = mfma16(hf1, wf[1][1], alo1);    \
    alo2 = mfma16(hf1, wf[2][1], alo2); alo3 = mfma16(hf1, wf[3][1], alo3);    \
    ahi0 = mfma16(hf3, wf[0][3], ahi0); ahi1 = mfma16(hf3, wf[1][3], ahi1);    \
    ahi2 = mfma16(hf3, wf[2][3], ahi2); ahi3 = mfma16(hf3, wf[3][3], ahi3);    \
    float zi_ = alo0[0] + ahi0[0];                                             \
    float zf_ = alo1[0] + ahi1[0];                                             \
    float zg_ = alo2[0] + ahi2[0];                                             \
    float zo_ = alo3[0] + ahi3[0];                                             \
    float fi = sigf(zi_), ff = sigf(zf_);                                      \
    float tg = tanhf_(zg_), fo = sigf(zo_);                                    \
    cr = ff*cr + fi*tg;                                                        \
    u16 hp = f2bf(fo * tanhf_(cr));                                            \
    hb[WB][hwr] = hp;                                                          \
    asm volatile("s_waitcnt lgkmcnt(0)" ::: "memory");                         \
    __builtin_amdgcn_s_barrier();                                              \
    cat[catlane + catoff] = hp;                                                \
    catoff += catstep;                                                         \
  }

  for (int t = 0; t < 512; t += 4){
    SCAN_STEP(t,   0, 1, 0)
    SCAN_STEP(t+1, 1, 0, 1)
    SCAN_STEP(t+2, 0, 1, 2)
    SCAN_STEP(t+3, 1, 0, 3)
  }
#undef SCAN_STEP
}

// ---------------- residual + LayerNorm (sums two split-K partials) ----------------
__global__ __launch_bounds__(256) void k_ln(const float* __restrict__ emb, const float* __restrict__ p0,
                     const float* __restrict__ p1,
                     const float* __restrict__ gamma, const float* __restrict__ beta,
                     float* __restrict__ out)
{
  int row = blockIdx.x, tid = threadIdx.x;
  const float* pe = emb + (size_t)row * 768;
  const float* pa = p0 + (size_t)row * 768;
  const float* pb = p1 + (size_t)row * 768;
  float v0 = pe[tid]     + pa[tid]     + pb[tid];
  float v1 = pe[tid+256] + pa[tid+256] + pb[tid+256];
  float v2 = pe[tid+512] + pa[tid+512] + pb[tid+512];
  float s = v0+v1+v2, s2 = v0*v0+v1*v1+v2*v2;
  #pragma unroll
  for (int o = 32; o > 0; o >>= 1){ s += __shfl_down(s, o); s2 += __shfl_down(s2, o); }
  __shared__ float rs[4], rq[4];
  int wv = tid >> 6;
  if ((tid & 63) == 0){ rs[wv] = s; rq[wv] = s2; }
  __syncthreads();
  s = rs[0]+rs[1]+rs[2]+rs[3];
  s2 = rq[0]+rq[1]+rq[2]+rq[3];
  float mu = s * (1.0f/768.0f);
  float var = s2 * (1.0f/768.0f) - mu*mu;
  float rr = rsqrtf(var + 1e-5f);
  float* po = out + (size_t)row * 768;
  po[tid]     = (v0-mu)*rr*gamma[tid]     + beta[tid];
  po[tid+256] = (v1-mu)*rr*gamma[tid+256] + beta[tid+256];
  po[tid+512] = (v2-mu)*rr*gamma[tid+512] + beta[tid+512];
}

extern "C" void kernel_launch(void* const* d_in, const int* in_sizes, int n_in,
                              void* d_out, int out_size, void* d_ws, size_t ws_size,
                              hipStream_t stream)
{
  const float* emb   = (const float*)d_in[0];
  const float* W_ih  = (const float*)d_in[1];
  const float* W_hh  = (const float*)d_in[2];
  const float* b_ih  = (const float*)d_in[3];
  const float* b_hh  = (const float*)d_in[4];
  const float* W_int = (const float*)d_in[5];
  const float* b_int = (const float*)d_in[6];
  const float* W_out = (const float*)d_in[7];
  const float* b_out = (const float*)d_in[8];
  const float* gamma = (const float*)d_in[9];
  const float* beta  = (const float*)d_in[10];
  float* out = (float*)d_out;

  char* ws = (char*)d_ws;
  u16* embb  = (u16*)(ws + 0);           // 12,582,912
  u16* wihb  = (u16*)(ws + 12582912);    //  9,437,184
  u16* whhb  = (u16*)(ws + 22020096);    //  1,572,864
  u16* wintb = (u16*)(ws + 23592960);    //  9,437,184
  u16* woutb = (u16*)(ws + 33030144);    //  4,718,592
  u16* catb  = (u16*)(ws + 37748736);    // 25,165,824 (dead after GEMM1)
  float* proj1=(float*)(ws + 37748736);  // 25,165,824 (overlays catb)
  u16* xp    = (u16*)(ws + 62914560);    // 100,663,296 (dead after scan)
  u16* interb= (u16*)(ws + 62914560);    // 50,331,648 (reuses xp)
  float* proj0=(float*)(ws + 113246208); // 25,165,824 (reuses xp tail)

  auto cast = [&](const float* src, u16* dst, int n){
    int n4 = n >> 2;
    hipLaunchKernelGGL(k_cast, dim3((n4+255)/256), dim3(256), 0, stream, src, dst, n4);
  };
  cast(emb,   embb,  6291456);
  cast(W_ih,  wihb,  4718592);
  cast(W_hh,  whhb,   786432);
  cast(W_int, wintb, 4718592);
  cast(W_out, woutb, 2359296);

  // x-projection: [8192,768] x [6144,768]^T -> xp row-major (bias baked in)
  hipLaunchKernelGGL((k_gemm<0>), dim3(3072), dim3(256), 0, stream,
                     embb, wihb, (void*)xp, nullptr, b_ih, b_hh, 8192, 6144, 768, 768);
  // sequential BiLSTM scan -> cat [16,512,1536] bf16
  hipLaunchKernelGGL(k_scan, dim3(48), dim3(512), 0, stream, whhb, xp, catb);
  // FFN up + gelu: [8192,1536] x [3072,1536]^T -> inter bf16
  hipLaunchKernelGGL((k_gemm<1>), dim3(1536), dim3(256), 0, stream,
                     catb, wintb, (void*)interb, nullptr, b_int, nullptr, 8192, 3072, 1536, 1536);
  // FFN down, split-K x2: [8192,3072] x [768,3072]^T -> proj0 (half0) + proj1 (half1)
  hipLaunchKernelGGL((k_gemm<2>), dim3(768), dim3(256), 0, stream,
                     interb, woutb, (void*)proj0, (void*)proj1, b_out, nullptr, 8192, 768, 1536, 3072);
  // residual + LayerNorm
  hipLaunchKernelGGL(k_ln, dim3(8192), dim3(256), 0, stream, emb, proj0, proj1, gamma, beta, out);
}